// Round 1
// baseline (51019.839 us; speedup 1.0000x reference)
//
#include <hip/hip_runtime.h>
#include <hip/hip_bf16.h>

// LSTM T=8192, I=620, H=1000, batch=1.
// Phase 1: xg[t][4000] = x[t] @ W_ih^T + (b_ih+b_hh)   (parallel GEMM -> ws)
// Phase 2: persistent 50-WG kernel, one-way flag sync per step.

#define IN_SZ   620
#define HID     1000
#define G4      4000
#define NW      50      // workgroups in recurrent kernel
#define EP      20      // h elements per WG (NW*EP == HID)

__device__ __forceinline__ float sigmoidf_(float v) { return 1.0f / (1.0f + __expf(-v)); }

__device__ __forceinline__ void stxg_(float* p, float v) { *p = v; }
__device__ __forceinline__ void stxg_(__hip_bfloat16* p, float v) { *p = __float2bfloat16(v); }

// ---------------- Phase 1: xg GEMM (fp32 vector, 64x64x62 tiles) ----------------
template <typename XG>
__global__ __launch_bounds__(256) void xg_gemm(
    const float* __restrict__ x,    // (T, 620)
    const float* __restrict__ Wih,  // (4000, 620)
    const float* __restrict__ bih,
    const float* __restrict__ bhh,
    XG* __restrict__ xg,            // (T, 4000)
    int T)
{
    constexpr int BM = 64, BN = 64, BK = 62, LDK = 63; // +1 pad vs 62 to break conflicts
    __shared__ float As[BM][LDK];
    __shared__ float Bs[BN][LDK];
    const int tid = threadIdx.x;
    const int tx = tid & 15, ty = tid >> 4;
    const int m0 = blockIdx.y * BM, n0 = blockIdx.x * BN;
    float acc[4][4] = {};

    for (int k0 = 0; k0 < IN_SZ; k0 += BK) {
        for (int idx = tid; idx < BM * BK; idx += 256) {
            int r = idx / BK, c = idx - r * BK;
            int m = m0 + r;
            As[r][c] = (m < T) ? x[(size_t)m * IN_SZ + k0 + c] : 0.0f;
        }
        for (int idx = tid; idx < BN * BK; idx += 256) {
            int r = idx / BK, c = idx - r * BK;
            int n = n0 + r;
            Bs[r][c] = (n < G4) ? Wih[(size_t)n * IN_SZ + k0 + c] : 0.0f;
        }
        __syncthreads();
        for (int kk = 0; kk < BK; ++kk) {
            float a[4], b[4];
            #pragma unroll
            for (int i = 0; i < 4; ++i) a[i] = As[ty * 4 + i][kk];
            #pragma unroll
            for (int j = 0; j < 4; ++j) b[j] = Bs[tx * 4 + j][kk];
            #pragma unroll
            for (int i = 0; i < 4; ++i)
                #pragma unroll
                for (int j = 0; j < 4; ++j)
                    acc[i][j] = fmaf(a[i], b[j], acc[i][j]);
        }
        __syncthreads();
    }

    #pragma unroll
    for (int j = 0; j < 4; ++j) {
        int n = n0 + tx * 4 + j;
        if (n >= G4) continue;
        float bias = bih[n] + bhh[n];
        #pragma unroll
        for (int i = 0; i < 4; ++i) {
            int m = m0 + ty * 4 + i;
            if (m < T) stxg_(&xg[(size_t)m * G4 + n], acc[i][j] + bias);
        }
    }
}

// ---------------- Phase 2: persistent recurrent kernel ----------------
// MODE 0: xg precomputed fp32; MODE 1: xg bf16; MODE 2: fused x-projection (no xg buffer).
template <int MODE>
__global__ __launch_bounds__(256, 1) void lstm_seq(
    const void* __restrict__ xg_v,
    const float* __restrict__ x,     // MODE 2
    const float* __restrict__ Wih,   // MODE 2
    const float* __restrict__ Whh,   // (4000, 1000)
    const float* __restrict__ bih,   // MODE 2
    const float* __restrict__ bhh,   // MODE 2
    float* __restrict__ out,         // (T, 1000)
    float* hbuf,                     // 2 * 1024 floats (double buffer)
    unsigned* flags,                 // NW flags, stride 16 u32 (64B lines)
    int T)
{
    __shared__ __align__(16) float h_s[HID];
    __shared__ __align__(16) float x_s[IN_SZ + 4];
    __shared__ float pre[4][EP];
    __shared__ float c_s[EP];

    const int w = blockIdx.x, tid = threadIdx.x;
    const int wave = tid >> 6, lane = tid & 63;
    const int i16 = lane & 15, p = lane >> 4;
    const int e0 = w * EP;

    for (int i = tid; i < HID; i += 256) h_s[i] = 0.0f;
    if (tid < EP) c_s[tid] = 0.0f;
    if (MODE == 2) {
        for (int i = tid; i < IN_SZ; i += 256) x_s[i] = x[i];
    }
    __syncthreads();

    // this wave's 20 rows start here (gate == wave)
    const float* wb_h = Whh + ((size_t)wave * HID + e0) * HID;
    const float* wb_x = (MODE == 2) ? (Wih + ((size_t)wave * HID + e0) * IN_SZ) : nullptr;

    float bsum[4] = {0.f, 0.f, 0.f, 0.f};
    if (MODE == 2 && wave == 0 && lane < EP) {
        #pragma unroll
        for (int g = 0; g < 4; ++g) {
            int n = g * HID + e0 + lane;
            bsum[g] = bih[n] + bhh[n];
        }
    }

    for (int t = 0;;) {
        // xg terms for this step (issued early; completes under the dot-product passes)
        float xv[4] = {0.f, 0.f, 0.f, 0.f};
        if (wave == 0 && lane < EP) {
            if (MODE == 0) {
                const float* xr = (const float*)xg_v + (size_t)t * G4 + e0 + lane;
                xv[0] = xr[0]; xv[1] = xr[HID]; xv[2] = xr[2 * HID]; xv[3] = xr[3 * HID];
            } else if (MODE == 1) {
                const __hip_bfloat16* xr = (const __hip_bfloat16*)xg_v + (size_t)t * G4 + e0 + lane;
                xv[0] = __bfloat162float(xr[0]);
                xv[1] = __bfloat162float(xr[HID]);
                xv[2] = __bfloat162float(xr[2 * HID]);
                xv[3] = __bfloat162float(xr[3 * HID]);
            } else {
                xv[0] = bsum[0]; xv[1] = bsum[1]; xv[2] = bsum[2]; xv[3] = bsum[3];
            }
        }

        // 20 rows per wave; 4 rows in flight per pass, 16 lanes per row
        #pragma unroll
        for (int pass = 0; pass < EP / 4; ++pass) {
            const int e = pass * 4 + p;
            const float* wr = wb_h + (size_t)e * HID;
            float a0 = 0.f, a1 = 0.f, a2 = 0.f, a3 = 0.f;
            #pragma unroll
            for (int m = 0; m < 15; ++m) {
                const int k = i16 * 4 + m * 64;
                const float4 wv = *reinterpret_cast<const float4*>(wr + k);
                const float4 hv = *reinterpret_cast<const float4*>(&h_s[k]);
                const float s = fmaf(wv.x, hv.x, fmaf(wv.y, hv.y, fmaf(wv.z, hv.z, wv.w * hv.w)));
                if ((m & 3) == 0) a0 += s; else if ((m & 3) == 1) a1 += s;
                else if ((m & 3) == 2) a2 += s; else a3 += s;
            }
            if (i16 < 10) { // tail: k = 960..999
                const int k = i16 * 4 + 960;
                const float4 wv = *reinterpret_cast<const float4*>(wr + k);
                const float4 hv = *reinterpret_cast<const float4*>(&h_s[k]);
                a3 += fmaf(wv.x, hv.x, fmaf(wv.y, hv.y, fmaf(wv.z, hv.z, wv.w * hv.w)));
            }
            if (MODE == 2) { // fused x-projection
                const float* wrx = wb_x + (size_t)e * IN_SZ;
                #pragma unroll
                for (int m = 0; m < 9; ++m) {
                    const int k = i16 * 4 + m * 64;
                    const float4 wv = *reinterpret_cast<const float4*>(wrx + k);
                    const float4 hv = *reinterpret_cast<const float4*>(&x_s[k]);
                    const float s = fmaf(wv.x, hv.x, fmaf(wv.y, hv.y, fmaf(wv.z, hv.z, wv.w * hv.w)));
                    if ((m & 3) == 0) a0 += s; else if ((m & 3) == 1) a1 += s;
                    else if ((m & 3) == 2) a2 += s; else a3 += s;
                }
                if (i16 < 11) { // tail: k = 576..619
                    const int k = i16 * 4 + 576;
                    const float4 wv = *reinterpret_cast<const float4*>(wrx + k);
                    const float4 hv = *reinterpret_cast<const float4*>(&x_s[k]);
                    a3 += fmaf(wv.x, hv.x, fmaf(wv.y, hv.y, fmaf(wv.z, hv.z, wv.w * hv.w)));
                }
            }
            float acc = (a0 + a1) + (a2 + a3);
            acc += __shfl_xor(acc, 1);
            acc += __shfl_xor(acc, 2);
            acc += __shfl_xor(acc, 4);
            acc += __shfl_xor(acc, 8);
            if (i16 == 0) pre[wave][e] = acc;
        }
        __syncthreads();

        // finalize gates, update c, publish h (wave 0 only)
        if (wave == 0 && lane < EP) {
            const float gi = pre[0][lane] + xv[0];
            const float gf = pre[1][lane] + xv[1];
            const float gg = pre[2][lane] + xv[2];
            const float go = pre[3][lane] + xv[3];
            const float iv = sigmoidf_(gi);
            const float fv = sigmoidf_(gf);
            const float gv = tanhf(gg);
            const float ov = sigmoidf_(go);
            const float c = fv * c_s[lane] + iv * gv;
            c_s[lane] = c;
            const float h = ov * tanhf(c);
            out[(size_t)t * HID + e0 + lane] = h;
            if (t + 1 < T) {
                // agent-scope store: write through past the (non-coherent) per-XCD L2
                __hip_atomic_store(&hbuf[(t & 1) * 1024 + e0 + lane], h,
                                   __ATOMIC_RELAXED, __HIP_MEMORY_SCOPE_AGENT);
            }
        }

        if (++t >= T) break;

        // release-publish our step flag (orders the wave's prior h stores)
        if (tid == 0) {
            __hip_atomic_store(&flags[w * 16], (unsigned)t,
                               __ATOMIC_RELEASE, __HIP_MEMORY_SCOPE_AGENT);
        }
        // one-way wait: all producers published step t
        if (wave == 0 && lane < NW) {
            while (__hip_atomic_load(&flags[lane * 16],
                                     __ATOMIC_RELAXED, __HIP_MEMORY_SCOPE_AGENT) < (unsigned)t) {
                __builtin_amdgcn_s_sleep(1);
            }
        }
        __syncthreads();

        // fetch new h (agent-scope loads bypass stale L2; weights stay L2-resident)
        for (int i = tid; i < HID; i += 256) {
            h_s[i] = __hip_atomic_load(&hbuf[((t - 1) & 1) * 1024 + i],
                                       __ATOMIC_RELAXED, __HIP_MEMORY_SCOPE_AGENT);
        }
        if (MODE == 2) {
            for (int i = tid; i < IN_SZ; i += 256) x_s[i] = x[(size_t)t * IN_SZ + i];
        }
        __syncthreads();
    }
}

// ---------------- launch ----------------
extern "C" void kernel_launch(void* const* d_in, const int* in_sizes, int n_in,
                              void* d_out, int out_size, void* d_ws, size_t ws_size,
                              hipStream_t stream)
{
    const float* x   = (const float*)d_in[0];
    const float* Wih = (const float*)d_in[1];
    const float* Whh = (const float*)d_in[2];
    const float* bih = (const float*)d_in[3];
    const float* bhh = (const float*)d_in[4];
    float* out = (float*)d_out;
    const int T = in_sizes[0] / IN_SZ;

    char* ws = (char*)d_ws;
    float* hbuf = (float*)ws;                  // 2*1024 floats = 8 KB
    unsigned* flags = (unsigned*)(ws + 8192);  // NW * 64B
    const size_t CTRL = 16384;
    hipMemsetAsync(d_ws, 0, CTRL, stream);     // zero h-buffers + flags every call

    const size_t need32 = CTRL + (size_t)T * G4 * sizeof(float);
    const size_t need16 = CTRL + (size_t)T * G4 * sizeof(__hip_bfloat16);

    dim3 g1((G4 + 63) / 64, (T + 63) / 64), b1(256);
    dim3 g2(NW), b2(256);

    if (ws_size >= need32) {
        float* xgbuf = (float*)(ws + CTRL);
        xg_gemm<float><<<g1, b1, 0, stream>>>(x, Wih, bih, bhh, xgbuf, T);
        lstm_seq<0><<<g2, b2, 0, stream>>>(xgbuf, x, Wih, Whh, bih, bhh, out, hbuf, flags, T);
    } else if (ws_size >= need16) {
        __hip_bfloat16* xgbuf = (__hip_bfloat16*)(ws + CTRL);
        xg_gemm<__hip_bfloat16><<<g1, b1, 0, stream>>>(x, Wih, bih, bhh, xgbuf, T);
        lstm_seq<1><<<g2, b2, 0, stream>>>(xgbuf, x, Wih, Whh, bih, bhh, out, hbuf, flags, T);
    } else {
        lstm_seq<2><<<g2, b2, 0, stream>>>(nullptr, x, Wih, Whh, bih, bhh, out, hbuf, flags, T);
    }
}

// Round 2
// 50598.621 us; speedup vs baseline: 1.0083x; 1.0083x over previous
//
#include <hip/hip_runtime.h>
#include <hip/hip_bf16.h>

// LSTM T=8192, I=620, H=1000, batch=1.
// Phase 1: xg[t][4000] = x[t] @ W_ih^T + (b_ih+b_hh)   (parallel GEMM -> ws)
// Phase 2: persistent 50-WG kernel; contiguous-flag one-way sync; wave-role split.

#define IN_SZ   620
#define HID     1000
#define G4      4000
#define NW      50      // workgroups in recurrent kernel
#define EP      20      // h elements per WG (NW*EP == HID)

__device__ __forceinline__ float sigm(float v)      { return 1.0f / (1.0f + __expf(-v)); }
__device__ __forceinline__ float tanh_fast(float v) { return 2.0f / (1.0f + __expf(-2.0f * v)) - 1.0f; }

__device__ __forceinline__ void stxg_(float* p, float v) { *p = v; }
__device__ __forceinline__ void stxg_(__hip_bfloat16* p, float v) { *p = __float2bfloat16(v); }

// ---------------- Phase 1: xg GEMM (fp32 vector, 64x64x62 tiles) ----------------
template <typename XG>
__global__ __launch_bounds__(256) void xg_gemm(
    const float* __restrict__ x,    // (T, 620)
    const float* __restrict__ Wih,  // (4000, 620)
    const float* __restrict__ bih,
    const float* __restrict__ bhh,
    XG* __restrict__ xg,            // (T, 4000)
    int T)
{
    constexpr int BM = 64, BN = 64, BK = 62, LDK = 63;
    __shared__ float As[BM][LDK];
    __shared__ float Bs[BN][LDK];
    const int tid = threadIdx.x;
    const int tx = tid & 15, ty = tid >> 4;
    const int m0 = blockIdx.y * BM, n0 = blockIdx.x * BN;
    float acc[4][4] = {};

    for (int k0 = 0; k0 < IN_SZ; k0 += BK) {
        for (int idx = tid; idx < BM * BK; idx += 256) {
            int r = idx / BK, c = idx - r * BK;
            int m = m0 + r;
            As[r][c] = (m < T) ? x[(size_t)m * IN_SZ + k0 + c] : 0.0f;
        }
        for (int idx = tid; idx < BN * BK; idx += 256) {
            int r = idx / BK, c = idx - r * BK;
            int n = n0 + r;
            Bs[r][c] = (n < G4) ? Wih[(size_t)n * IN_SZ + k0 + c] : 0.0f;
        }
        __syncthreads();
        for (int kk = 0; kk < BK; ++kk) {
            float a[4], b[4];
            #pragma unroll
            for (int i = 0; i < 4; ++i) a[i] = As[ty * 4 + i][kk];
            #pragma unroll
            for (int j = 0; j < 4; ++j) b[j] = Bs[tx * 4 + j][kk];
            #pragma unroll
            for (int i = 0; i < 4; ++i)
                #pragma unroll
                for (int j = 0; j < 4; ++j)
                    acc[i][j] = fmaf(a[i], b[j], acc[i][j]);
        }
        __syncthreads();
    }

    #pragma unroll
    for (int j = 0; j < 4; ++j) {
        int n = n0 + tx * 4 + j;
        if (n >= G4) continue;
        float bias = bih[n] + bhh[n];
        #pragma unroll
        for (int i = 0; i < 4; ++i) {
            int m = m0 + ty * 4 + i;
            if (m < T) stxg_(&xg[(size_t)m * G4 + n], acc[i][j] + bias);
        }
    }
}

// ---------------- Phase 2: persistent recurrent kernel ----------------
// MODE 0: xg fp32; MODE 1: xg bf16; MODE 2: fused x-projection.
template <int MODE>
__global__ __launch_bounds__(256, 1) void lstm_seq(
    const void* __restrict__ xg_v,
    const float* __restrict__ x,
    const float* __restrict__ Wih,
    const float* __restrict__ Whh,   // (4000, 1000)
    const float* __restrict__ bih,
    const float* __restrict__ bhh,
    float* __restrict__ out,         // (T, 1000)
    float* hbuf,                     // 2 * 1024 floats (double buffer)
    unsigned* flags,                 // NW contiguous u32
    int T)
{
    __shared__ __align__(16) float h_s[HID];
    __shared__ __align__(16) float x_s[IN_SZ + 4];
    __shared__ float pre[4][EP];

    const int w = blockIdx.x, tid = threadIdx.x;
    const int wave = tid >> 6, lane = tid & 63;
    const int i16 = lane & 15, p = lane >> 4;
    const int e0 = w * EP;

    for (int i = tid; i < HID; i += 256) h_s[i] = 0.0f;
    if (MODE == 2) {
        for (int i = tid; i < IN_SZ; i += 256) x_s[i] = x[i];
    }
    __syncthreads();

    const float* wb_h = Whh + ((size_t)wave * HID + e0) * HID;
    const float* wb_x = (MODE == 2) ? (Wih + ((size_t)wave * HID + e0) * IN_SZ) : nullptr;

    float c_reg = 0.0f;              // cell state, wave0 lanes<EP
    float bsum[4] = {0.f, 0.f, 0.f, 0.f};
    if (MODE == 2 && wave == 0 && lane < EP) {
        #pragma unroll
        for (int g = 0; g < 4; ++g) {
            int n = g * HID + e0 + lane;
            bsum[g] = bih[n] + bhh[n];
        }
    }

    for (int t = 0;;) {
        // xg terms for this step (independent of h; completes under the dot passes)
        float xv[4] = {0.f, 0.f, 0.f, 0.f};
        if (wave == 0 && lane < EP) {
            if (MODE == 0) {
                const float* xr = (const float*)xg_v + (size_t)t * G4 + e0 + lane;
                xv[0] = xr[0]; xv[1] = xr[HID]; xv[2] = xr[2 * HID]; xv[3] = xr[3 * HID];
            } else if (MODE == 1) {
                const __hip_bfloat16* xr = (const __hip_bfloat16*)xg_v + (size_t)t * G4 + e0 + lane;
                xv[0] = __bfloat162float(xr[0]);
                xv[1] = __bfloat162float(xr[HID]);
                xv[2] = __bfloat162float(xr[2 * HID]);
                xv[3] = __bfloat162float(xr[3 * HID]);
            } else {
                xv[0] = bsum[0]; xv[1] = bsum[1]; xv[2] = bsum[2]; xv[3] = bsum[3];
            }
        }

        // 20 rows per wave (gate == wave); 4 rows in flight, 16 lanes per row
        #pragma unroll
        for (int pass = 0; pass < EP / 4; ++pass) {
            const int e = pass * 4 + p;
            const float* wr = wb_h + (size_t)e * HID;
            float a0 = 0.f, a1 = 0.f, a2 = 0.f, a3 = 0.f;
            #pragma unroll
            for (int m = 0; m < 15; ++m) {
                const int k = i16 * 4 + m * 64;
                const float4 wv = *reinterpret_cast<const float4*>(wr + k);
                const float4 hv = *reinterpret_cast<const float4*>(&h_s[k]);
                const float s = fmaf(wv.x, hv.x, fmaf(wv.y, hv.y, fmaf(wv.z, hv.z, wv.w * hv.w)));
                if ((m & 3) == 0) a0 += s; else if ((m & 3) == 1) a1 += s;
                else if ((m & 3) == 2) a2 += s; else a3 += s;
            }
            if (i16 < 10) { // tail: k = 960..999
                const int k = i16 * 4 + 960;
                const float4 wv = *reinterpret_cast<const float4*>(wr + k);
                const float4 hv = *reinterpret_cast<const float4*>(&h_s[k]);
                a3 += fmaf(wv.x, hv.x, fmaf(wv.y, hv.y, fmaf(wv.z, hv.z, wv.w * hv.w)));
            }
            if (MODE == 2) {
                const float* wrx = wb_x + (size_t)e * IN_SZ;
                #pragma unroll
                for (int m = 0; m < 9; ++m) {
                    const int k = i16 * 4 + m * 64;
                    const float4 wv = *reinterpret_cast<const float4*>(wrx + k);
                    const float4 hv = *reinterpret_cast<const float4*>(&x_s[k]);
                    const float s = fmaf(wv.x, hv.x, fmaf(wv.y, hv.y, fmaf(wv.z, hv.z, wv.w * hv.w)));
                    if ((m & 3) == 0) a0 += s; else if ((m & 3) == 1) a1 += s;
                    else if ((m & 3) == 2) a2 += s; else a3 += s;
                }
                if (i16 < 11) {
                    const int k = i16 * 4 + 576;
                    const float4 wv = *reinterpret_cast<const float4*>(wrx + k);
                    const float4 hv = *reinterpret_cast<const float4*>(&x_s[k]);
                    a3 += fmaf(wv.x, hv.x, fmaf(wv.y, hv.y, fmaf(wv.z, hv.z, wv.w * hv.w)));
                }
            }
            float acc = (a0 + a1) + (a2 + a3);
            acc += __shfl_xor(acc, 1);
            acc += __shfl_xor(acc, 2);
            acc += __shfl_xor(acc, 4);
            acc += __shfl_xor(acc, 8);
            if (i16 == 0) pre[wave][e] = acc;
        }
        __syncthreads();   // barrier 1: pre[] ready, h_s reads done

        // wave 0: finalize gates, update c, publish h + flag
        if (wave == 0 && lane < EP) {
            const float gi = pre[0][lane] + xv[0];
            const float gf = pre[1][lane] + xv[1];
            const float gg = pre[2][lane] + xv[2];
            const float go = pre[3][lane] + xv[3];
            const float iv = sigm(gi);
            const float fv = sigm(gf);
            const float gv = tanh_fast(gg);
            const float ov = sigm(go);
            c_reg = fv * c_reg + iv * gv;
            const float h = ov * tanh_fast(c_reg);
            out[(size_t)t * HID + e0 + lane] = h;
            // write-through past the (non-coherent) per-XCD L2
            __hip_atomic_store(&hbuf[(t & 1) * 1024 + e0 + lane], h,
                               __ATOMIC_RELAXED, __HIP_MEMORY_SCOPE_AGENT);
        }

        if (++t >= T) break;

        if (wave == 0 && lane == 0) {
            asm volatile("s_waitcnt vmcnt(0)" ::: "memory");  // h stores visible first
            __hip_atomic_store(&flags[w], (unsigned)t,
                               __ATOMIC_RELAXED, __HIP_MEMORY_SCOPE_AGENT);
        }

        // waves 1-3: poll all producers, then refill h_s (wave 0 skips: barrier2 gates it)
        if (wave > 0) {
            if (lane < NW) {
                while (__hip_atomic_load(&flags[lane], __ATOMIC_RELAXED,
                                         __HIP_MEMORY_SCOPE_AGENT) < (unsigned)t) {}
            }
            const int rb = tid - 64;                 // 0..191
            const float4* src = (const float4*)(hbuf + ((t - 1) & 1) * 1024);
            const int i0 = rb;                       // < 250 always
            const int i1 = rb + 192;                 // valid if < 250
            float4 a, b;
            asm volatile(
                "global_load_dwordx4 %0, %2, off sc0 sc1\n\t"
                "global_load_dwordx4 %1, %3, off sc0 sc1\n\t"
                "s_waitcnt vmcnt(0)"
                : "=&v"(a), "=&v"(b)
                : "v"(src + i0), "v"(src + (i1 < 250 ? i1 : 0))
                : "memory");
            ((float4*)h_s)[i0] = a;
            if (i1 < 250) ((float4*)h_s)[i1] = b;
            if (MODE == 2) {
                for (int i = rb; i < IN_SZ; i += 192) x_s[i] = x[(size_t)t * IN_SZ + i];
            }
        }
        __syncthreads();   // barrier 2: h_s (and x_s) ready
    }
}

// ---------------- launch ----------------
extern "C" void kernel_launch(void* const* d_in, const int* in_sizes, int n_in,
                              void* d_out, int out_size, void* d_ws, size_t ws_size,
                              hipStream_t stream)
{
    const float* x   = (const float*)d_in[0];
    const float* Wih = (const float*)d_in[1];
    const float* Whh = (const float*)d_in[2];
    const float* bih = (const float*)d_in[3];
    const float* bhh = (const float*)d_in[4];
    float* out = (float*)d_out;
    const int T = in_sizes[0] / IN_SZ;

    char* ws = (char*)d_ws;
    float* hbuf = (float*)ws;                  // 2*1024 floats = 8 KB
    unsigned* flags = (unsigned*)(ws + 8192);  // NW contiguous u32
    const size_t CTRL = 16384;
    hipMemsetAsync(d_ws, 0, CTRL, stream);     // zero h-buffers + flags every call

    const size_t need32 = CTRL + (size_t)T * G4 * sizeof(float);
    const size_t need16 = CTRL + (size_t)T * G4 * sizeof(__hip_bfloat16);

    dim3 g1((G4 + 63) / 64, (T + 63) / 64), b1(256);
    dim3 g2(NW), b2(256);

    if (ws_size >= need32) {
        float* xgbuf = (float*)(ws + CTRL);
        xg_gemm<float><<<g1, b1, 0, stream>>>(x, Wih, bih, bhh, xgbuf, T);
        lstm_seq<0><<<g2, b2, 0, stream>>>(xgbuf, x, Wih, Whh, bih, bhh, out, hbuf, flags, T);
    } else if (ws_size >= need16) {
        __hip_bfloat16* xgbuf = (__hip_bfloat16*)(ws + CTRL);
        xg_gemm<__hip_bfloat16><<<g1, b1, 0, stream>>>(x, Wih, bih, bhh, xgbuf, T);
        lstm_seq<1><<<g2, b2, 0, stream>>>(xgbuf, x, Wih, Whh, bih, bhh, out, hbuf, flags, T);
    } else {
        lstm_seq<2><<<g2, b2, 0, stream>>>(nullptr, x, Wih, Whh, bih, bhh, out, hbuf, flags, T);
    }
}

// Round 3
// 24621.126 us; speedup vs baseline: 2.0722x; 2.0551x over previous
//
#include <hip/hip_runtime.h>
#include <hip/hip_bf16.h>

// LSTM T=8192, I=620, H=1000, batch=1.
// Phase 1: xg[t][4000] = x[t] @ W_ih^T + (b_ih+b_hh)   (parallel GEMM -> ws)
// Phase 2: 125-WG persistent kernel. W_hh lives entirely in REGISTERS
//          (125 fp32/lane). Sync = stamped self-validating publish:
//          2 mantissa LSBs of each published h word carry (t+1)&3, consumers
//          retry dwordx4 sc0/sc1 gathers until all stamps match -> ONE L3
//          round trip for detect+data, no flags, one barrier per step.

#define IN_SZ   620
#define HID     1000
#define G4      4000
#define NWF     125     // fast-kernel workgroups
#define NW_LEG  50      // legacy fallback workgroups
#define EP_LEG  20

__device__ __forceinline__ float sigm(float v)      { return 1.0f / (1.0f + __expf(-v)); }
__device__ __forceinline__ float tanh_fast(float v) { return 2.0f / (1.0f + __expf(-2.0f * v)) - 1.0f; }

__device__ __forceinline__ void stxg_(float* p, float v) { *p = v; }
__device__ __forceinline__ void stxg_(__hip_bfloat16* p, float v) { *p = __float2bfloat16(v); }

// ---------------- Phase 1: xg GEMM (fp32 vector, 64x64x62 tiles) ----------------
template <typename XG>
__global__ __launch_bounds__(256) void xg_gemm(
    const float* __restrict__ x,    // (T, 620)
    const float* __restrict__ Wih,  // (4000, 620)
    const float* __restrict__ bih,
    const float* __restrict__ bhh,
    XG* __restrict__ xg,            // (T, 4000)
    int T)
{
    constexpr int BM = 64, BN = 64, BK = 62, LDK = 63;
    __shared__ float As[BM][LDK];
    __shared__ float Bs[BN][LDK];
    const int tid = threadIdx.x;
    const int tx = tid & 15, ty = tid >> 4;
    const int m0 = blockIdx.y * BM, n0 = blockIdx.x * BN;
    float acc[4][4] = {};

    for (int k0 = 0; k0 < IN_SZ; k0 += BK) {
        for (int idx = tid; idx < BM * BK; idx += 256) {
            int r = idx / BK, c = idx - r * BK;
            int m = m0 + r;
            As[r][c] = (m < T) ? x[(size_t)m * IN_SZ + k0 + c] : 0.0f;
        }
        for (int idx = tid; idx < BN * BK; idx += 256) {
            int r = idx / BK, c = idx - r * BK;
            int n = n0 + r;
            Bs[r][c] = (n < G4) ? Wih[(size_t)n * IN_SZ + k0 + c] : 0.0f;
        }
        __syncthreads();
        for (int kk = 0; kk < BK; ++kk) {
            float a[4], b[4];
            #pragma unroll
            for (int i = 0; i < 4; ++i) a[i] = As[ty * 4 + i][kk];
            #pragma unroll
            for (int j = 0; j < 4; ++j) b[j] = Bs[tx * 4 + j][kk];
            #pragma unroll
            for (int i = 0; i < 4; ++i)
                #pragma unroll
                for (int j = 0; j < 4; ++j)
                    acc[i][j] = fmaf(a[i], b[j], acc[i][j]);
        }
        __syncthreads();
    }

    #pragma unroll
    for (int j = 0; j < 4; ++j) {
        int n = n0 + tx * 4 + j;
        if (n >= G4) continue;
        float bias = bih[n] + bhh[n];
        #pragma unroll
        for (int i = 0; i < 4; ++i) {
            int m = m0 + ty * 4 + i;
            if (m < T) stxg_(&xg[(size_t)m * G4 + n], acc[i][j] + bias);
        }
    }
}

// ---------------- Phase 2: register-resident recurrent kernel ----------------
// MODE 0: xg fp32; MODE 1: xg bf16.
template <int MODE>
__global__ __launch_bounds__(256, 1) void lstm_fast(
    const void* __restrict__ xg_v,
    const float* __restrict__ Whh,   // (4000, 1000)
    float* __restrict__ out,         // (T, 1000)
    unsigned* hb_u,                  // 2 * 1024 u32 (double-buffered, stamped)
    int T)
{
    __shared__ __align__(16) unsigned hs[2][1024];
    __shared__ float gsum[4][4][2];  // [wave][gate][elem-parity]

    const int w = blockIdx.x, tid = threadIdx.x;
    const int wave = tid >> 6, lane = tid & 63;
    const int i16 = lane & 15, p = lane >> 4;       // p = gate (0..3)
    const int we0 = w * 8 + wave * 2;               // this wave's 2 h-elements

    for (int i = tid; i < 2048; i += 256) ((unsigned*)hs)[i] = 0u;
    __syncthreads();

    // ---- weight preload into registers: rows (p*HID + we0) and (.. + 1) ----
    const size_t rowA = (size_t)(p * HID + we0) * HID;
    const size_t rowB = rowA + HID;
    float4 wA[16], wB[16], hreg[16];
    #pragma unroll
    for (int m = 0; m < 15; ++m) {
        wA[m] = *reinterpret_cast<const float4*>(Whh + rowA + i16 * 4 + m * 64);
        wB[m] = *reinterpret_cast<const float4*>(Whh + rowB + i16 * 4 + m * 64);
    }
    if (i16 < 10) {
        wA[15] = *reinterpret_cast<const float4*>(Whh + rowA + 960 + i16 * 4);
        wB[15] = *reinterpret_cast<const float4*>(Whh + rowB + 960 + i16 * 4);
    } else {
        wA[15] = float4{0.f, 0.f, 0.f, 0.f};
        wB[15] = float4{0.f, 0.f, 0.f, 0.f};
    }

    float c_reg = 0.0f;                              // lanes 0/1: cell state
    float xv0 = 0.f, xv1 = 0.f, xv2 = 0.f, xv3 = 0.f;
    if (lane < 2) {                                  // xg prefetch for t=0
        if (MODE == 0) {
            const float* xr = (const float*)xg_v + we0 + lane;
            xv0 = xr[0]; xv1 = xr[HID]; xv2 = xr[2 * HID]; xv3 = xr[3 * HID];
        } else {
            const __hip_bfloat16* xr = (const __hip_bfloat16*)xg_v + we0 + lane;
            xv0 = __bfloat162float(xr[0]);
            xv1 = __bfloat162float(xr[HID]);
            xv2 = __bfloat162float(xr[2 * HID]);
            xv3 = __bfloat162float(xr[3 * HID]);
        }
    }

    for (int t = 0;;) {
        const int rb = t & 1;

        // ---- h slice LDS -> regs ----
        #pragma unroll
        for (int m = 0; m < 15; ++m)
            hreg[m] = *reinterpret_cast<const float4*>(&hs[rb][i16 * 4 + m * 64]);
        hreg[15] = *reinterpret_cast<const float4*>(&hs[rb][960 + i16 * 4]);

        // ---- dot: 2 rows x 64 floats per lane, 8 independent FMA chains ----
        float a0 = 0.f, a1 = 0.f, a2 = 0.f, a3 = 0.f;
        float b0 = 0.f, b1 = 0.f, b2 = 0.f, b3 = 0.f;
        #pragma unroll
        for (int m = 0; m < 16; ++m) {
            const float4 hv = hreg[m];
            const float sA = fmaf(wA[m].x, hv.x, fmaf(wA[m].y, hv.y,
                             fmaf(wA[m].z, hv.z, wA[m].w * hv.w)));
            const float sB = fmaf(wB[m].x, hv.x, fmaf(wB[m].y, hv.y,
                             fmaf(wB[m].z, hv.z, wB[m].w * hv.w)));
            if ((m & 3) == 0)      { a0 += sA; b0 += sB; }
            else if ((m & 3) == 1) { a1 += sA; b1 += sB; }
            else if ((m & 3) == 2) { a2 += sA; b2 += sB; }
            else                   { a3 += sA; b3 += sB; }
        }
        float rA = (a0 + a1) + (a2 + a3);
        float rB = (b0 + b1) + (b2 + b3);
        rA += __shfl_xor(rA, 1); rB += __shfl_xor(rB, 1);
        rA += __shfl_xor(rA, 2); rB += __shfl_xor(rB, 2);
        rA += __shfl_xor(rA, 4); rB += __shfl_xor(rB, 4);
        rA += __shfl_xor(rA, 8); rB += __shfl_xor(rB, 8);
        if (i16 == 0) { gsum[wave][p][0] = rA; gsum[wave][p][1] = rB; }

        // ---- in-wave gates + publish (lanes 0/1; same-wave LDS, no barrier) ----
        if (lane < 2) {
            const float gi = gsum[wave][0][lane] + xv0;
            const float gf = gsum[wave][1][lane] + xv1;
            const float gg = gsum[wave][2][lane] + xv2;
            const float go = gsum[wave][3][lane] + xv3;
            const float iv = sigm(gi);
            const float fv = sigm(gf);
            const float gv = tanh_fast(gg);
            const float ov = sigm(go);
            c_reg = fv * c_reg + iv * gv;
            const float h = ov * tanh_fast(c_reg);
            out[(size_t)t * HID + we0 + lane] = h;
            const unsigned hb = (__float_as_uint(h) & ~3u) | (unsigned)((t + 1) & 3);
            __hip_atomic_store(hb_u + rb * 1024 + we0 + lane, hb,
                               __ATOMIC_RELAXED, __HIP_MEMORY_SCOPE_AGENT);
        }

        if (++t >= T) break;

        // ---- xg prefetch for next step (full iteration of latency hiding) ----
        if (lane < 2) {
            if (MODE == 0) {
                const float* xr = (const float*)xg_v + (size_t)t * G4 + we0 + lane;
                xv0 = xr[0]; xv1 = xr[HID]; xv2 = xr[2 * HID]; xv3 = xr[3 * HID];
            } else {
                const __hip_bfloat16* xr = (const __hip_bfloat16*)xg_v + (size_t)t * G4 + we0 + lane;
                xv0 = __bfloat162float(xr[0]);
                xv1 = __bfloat162float(xr[HID]);
                xv2 = __bfloat162float(xr[2 * HID]);
                xv3 = __bfloat162float(xr[3 * HID]);
            }
        }

        // ---- stamped gather of h^{t-1}: one RT, self-validating, retry ----
        if (tid < 250) {
            const unsigned want = (unsigned)t & 3u;          // ST(t-1) = t&3
            const uint4* src =
                reinterpret_cast<const uint4*>(hb_u + ((t - 1) & 1) * 1024) + tid;
            uint4 v;
            for (;;) {
                asm volatile("global_load_dwordx4 %0, %1, off sc0 sc1\n\t"
                             "s_waitcnt vmcnt(0)"
                             : "=&v"(v) : "v"(src) : "memory");
                if ((((v.x ^ want) | (v.y ^ want) | (v.z ^ want) | (v.w ^ want)) & 3u) == 0u)
                    break;
            }
            reinterpret_cast<uint4*>(&hs[rb ^ 1][0])[tid] = v;
        }
        __syncthreads();   // alternate h buffer ready
    }
}

// ---------------- legacy fallback (tiny ws): fused x-projection ----------------
__global__ __launch_bounds__(256, 1) void lstm_seq_legacy(
    const float* __restrict__ x,
    const float* __restrict__ Wih,
    const float* __restrict__ Whh,
    const float* __restrict__ bih,
    const float* __restrict__ bhh,
    float* __restrict__ out,
    float* hbuf, unsigned* flags, int T)
{
    __shared__ __align__(16) float h_s[HID];
    __shared__ __align__(16) float x_s[IN_SZ + 4];
    __shared__ float pre[4][EP_LEG];

    const int w = blockIdx.x, tid = threadIdx.x;
    const int wave = tid >> 6, lane = tid & 63;
    const int i16 = lane & 15, p = lane >> 4;
    const int e0 = w * EP_LEG;

    for (int i = tid; i < HID; i += 256) h_s[i] = 0.0f;
    for (int i = tid; i < IN_SZ; i += 256) x_s[i] = x[i];
    __syncthreads();

    const float* wb_h = Whh + ((size_t)wave * HID + e0) * HID;
    const float* wb_x = Wih + ((size_t)wave * HID + e0) * IN_SZ;
    float c_reg = 0.0f;
    float bsum[4] = {0.f, 0.f, 0.f, 0.f};
    if (wave == 0 && lane < EP_LEG) {
        #pragma unroll
        for (int g = 0; g < 4; ++g) {
            int n = g * HID + e0 + lane;
            bsum[g] = bih[n] + bhh[n];
        }
    }

    for (int t = 0;;) {
        #pragma unroll
        for (int pass = 0; pass < EP_LEG / 4; ++pass) {
            const int e = pass * 4 + p;
            const float* wr = wb_h + (size_t)e * HID;
            float a0 = 0.f, a1 = 0.f, a2 = 0.f, a3 = 0.f;
            #pragma unroll
            for (int m = 0; m < 15; ++m) {
                const int k = i16 * 4 + m * 64;
                const float4 wv = *reinterpret_cast<const float4*>(wr + k);
                const float4 hv = *reinterpret_cast<const float4*>(&h_s[k]);
                const float s = fmaf(wv.x, hv.x, fmaf(wv.y, hv.y, fmaf(wv.z, hv.z, wv.w * hv.w)));
                if ((m & 3) == 0) a0 += s; else if ((m & 3) == 1) a1 += s;
                else if ((m & 3) == 2) a2 += s; else a3 += s;
            }
            if (i16 < 10) {
                const int k = i16 * 4 + 960;
                const float4 wv = *reinterpret_cast<const float4*>(wr + k);
                const float4 hv = *reinterpret_cast<const float4*>(&h_s[k]);
                a3 += fmaf(wv.x, hv.x, fmaf(wv.y, hv.y, fmaf(wv.z, hv.z, wv.w * hv.w)));
            }
            const float* wrx = wb_x + (size_t)e * IN_SZ;
            #pragma unroll
            for (int m = 0; m < 9; ++m) {
                const int k = i16 * 4 + m * 64;
                const float4 wv = *reinterpret_cast<const float4*>(wrx + k);
                const float4 hv = *reinterpret_cast<const float4*>(&x_s[k]);
                const float s = fmaf(wv.x, hv.x, fmaf(wv.y, hv.y, fmaf(wv.z, hv.z, wv.w * hv.w)));
                if ((m & 3) == 0) a0 += s; else if ((m & 3) == 1) a1 += s;
                else if ((m & 3) == 2) a2 += s; else a3 += s;
            }
            if (i16 < 11) {
                const int k = i16 * 4 + 576;
                const float4 wv = *reinterpret_cast<const float4*>(wrx + k);
                const float4 hv = *reinterpret_cast<const float4*>(&x_s[k]);
                a3 += fmaf(wv.x, hv.x, fmaf(wv.y, hv.y, fmaf(wv.z, hv.z, wv.w * hv.w)));
            }
            float acc = (a0 + a1) + (a2 + a3);
            acc += __shfl_xor(acc, 1);
            acc += __shfl_xor(acc, 2);
            acc += __shfl_xor(acc, 4);
            acc += __shfl_xor(acc, 8);
            if (i16 == 0) pre[wave][e] = acc;
        }
        __syncthreads();

        if (wave == 0 && lane < EP_LEG) {
            const float gi = pre[0][lane] + bsum[0];
            const float gf = pre[1][lane] + bsum[1];
            const float gg = pre[2][lane] + bsum[2];
            const float go = pre[3][lane] + bsum[3];
            const float iv = sigm(gi);
            const float fv = sigm(gf);
            const float gv = tanh_fast(gg);
            const float ov = sigm(go);
            c_reg = fv * c_reg + iv * gv;
            const float h = ov * tanh_fast(c_reg);
            out[(size_t)t * HID + e0 + lane] = h;
            __hip_atomic_store(&hbuf[(t & 1) * 1024 + e0 + lane], h,
                               __ATOMIC_RELAXED, __HIP_MEMORY_SCOPE_AGENT);
        }
        if (++t >= T) break;
        if (wave == 0 && lane == 0) {
            asm volatile("s_waitcnt vmcnt(0)" ::: "memory");
            __hip_atomic_store(&flags[w], (unsigned)t,
                               __ATOMIC_RELAXED, __HIP_MEMORY_SCOPE_AGENT);
        }
        if (wave > 0) {
            if (lane < NW_LEG) {
                while (__hip_atomic_load(&flags[lane], __ATOMIC_RELAXED,
                                         __HIP_MEMORY_SCOPE_AGENT) < (unsigned)t) {}
            }
            const int rb = tid - 64;
            for (int i = rb; i < HID; i += 192) {
                h_s[i] = __hip_atomic_load(&hbuf[((t - 1) & 1) * 1024 + i],
                                           __ATOMIC_RELAXED, __HIP_MEMORY_SCOPE_AGENT);
            }
            for (int i = rb; i < IN_SZ; i += 192) x_s[i] = x[(size_t)t * IN_SZ + i];
        }
        __syncthreads();
    }
}

// ---------------- launch ----------------
extern "C" void kernel_launch(void* const* d_in, const int* in_sizes, int n_in,
                              void* d_out, int out_size, void* d_ws, size_t ws_size,
                              hipStream_t stream)
{
    const float* x   = (const float*)d_in[0];
    const float* Wih = (const float*)d_in[1];
    const float* Whh = (const float*)d_in[2];
    const float* bih = (const float*)d_in[3];
    const float* bhh = (const float*)d_in[4];
    float* out = (float*)d_out;
    const int T = in_sizes[0] / IN_SZ;

    char* ws = (char*)d_ws;
    unsigned* hb_u  = (unsigned*)ws;           // 2*1024 u32 = 8 KB (stamped h)
    unsigned* flags = (unsigned*)(ws + 8192);  // legacy only
    const size_t CTRL = 16384;
    hipMemsetAsync(d_ws, 0, CTRL, stream);     // zero h buffers + flags every call

    const size_t need32 = CTRL + (size_t)T * G4 * sizeof(float);
    const size_t need16 = CTRL + (size_t)T * G4 * sizeof(__hip_bfloat16);

    dim3 g1((G4 + 63) / 64, (T + 63) / 64), b1(256);

    if (ws_size >= need32) {
        float* xgbuf = (float*)(ws + CTRL);
        xg_gemm<float><<<g1, b1, 0, stream>>>(x, Wih, bih, bhh, xgbuf, T);
        lstm_fast<0><<<dim3(NWF), dim3(256), 0, stream>>>(xgbuf, Whh, out, hb_u, T);
    } else if (ws_size >= need16) {
        __hip_bfloat16* xgbuf = (__hip_bfloat16*)(ws + CTRL);
        xg_gemm<__hip_bfloat16><<<g1, b1, 0, stream>>>(x, Wih, bih, bhh, xgbuf, T);
        lstm_fast<1><<<dim3(NWF), dim3(256), 0, stream>>>(xgbuf, Whh, out, hb_u, T);
    } else {
        lstm_seq_legacy<<<dim3(NW_LEG), dim3(256), 0, stream>>>(
            x, Wih, Whh, bih, bhh, out, (float*)hb_u, flags, T);
    }
}

// Round 4
// 21067.110 us; speedup vs baseline: 2.4218x; 1.1687x over previous
//
#include <hip/hip_runtime.h>
#include <hip/hip_bf16.h>

// LSTM T=8192, I=620, H=1000, batch=1.
// Phase 1: xg[t][4000] = x[t] @ W_ih^T + (b_ih+b_hh)  (128x128x16 fp32 GEMM)
// Phase 2: 125-WG persistent kernel. W_hh in registers (2 rows/lane).
//   Per step: all waves dot -> gsum; bar1; wave0 finalizes gates (1 activation
//   per lane, shfl combine), publishes stamped h (2 mantissa LSBs = (t+1)&3),
//   prefetches next xg; waves 1-3 retry-gather stamped h with a CLEAN vmcnt
//   (they issue no stores) -> LDS; bar2.

#define IN_SZ   620
#define HID     1000
#define G4      4000
#define NWF     125     // fast-kernel workgroups
#define NW_LEG  50
#define EP_LEG  20

__device__ __forceinline__ float sigm(float v)      { return 1.0f / (1.0f + __expf(-v)); }
__device__ __forceinline__ float tanh_fast(float v) { return 2.0f / (1.0f + __expf(-2.0f * v)) - 1.0f; }

__device__ __forceinline__ void stxg_(float* p, float v) { *p = v; }
__device__ __forceinline__ void stxg_(__hip_bfloat16* p, float v) { *p = __float2bfloat16(v); }

// ---------------- Phase 1: xg GEMM, 128x128x16 tiles, 8x8 micro-tile ----------------
template <typename XG>
__global__ __launch_bounds__(256) void xg_gemm2(
    const float* __restrict__ x,    // (T, 620)
    const float* __restrict__ Wih,  // (4000, 620)
    const float* __restrict__ bih,
    const float* __restrict__ bhh,
    XG* __restrict__ xg,            // (T, 4000)
    int T)
{
    constexpr int BM = 128, BN = 128, BK = 16, LDT = BM + 4;
    __shared__ float As[BK][LDT];   // As[k][m]
    __shared__ float Bs[BK][LDT];   // Bs[k][n]
    const int tid = threadIdx.x;
    const int tx = tid & 15, ty = tid >> 4;
    const int m0 = blockIdx.y * BM, n0 = blockIdx.x * BN;
    float acc[8][8] = {};

    for (int k0 = 0; k0 < IN_SZ; k0 += BK) {
        #pragma unroll
        for (int it = 0; it < 2; ++it) {
            const int r = (tid >> 2) + it * 64;
            const int c = (tid & 3) * 4;
            const int gk = k0 + c;
            // A tile
            {
                const int gm = m0 + r;
                float4 v = {0.f, 0.f, 0.f, 0.f};
                if (gm < T) {
                    if (gk + 3 < IN_SZ) {
                        v = *reinterpret_cast<const float4*>(x + (size_t)gm * IN_SZ + gk);
                    } else {
                        const float* row = x + (size_t)gm * IN_SZ;
                        v.x = (gk + 0 < IN_SZ) ? row[gk + 0] : 0.f;
                        v.y = (gk + 1 < IN_SZ) ? row[gk + 1] : 0.f;
                        v.z = (gk + 2 < IN_SZ) ? row[gk + 2] : 0.f;
                        v.w = (gk + 3 < IN_SZ) ? row[gk + 3] : 0.f;
                    }
                }
                As[c + 0][r] = v.x; As[c + 1][r] = v.y;
                As[c + 2][r] = v.z; As[c + 3][r] = v.w;
            }
            // B tile
            {
                const int gn = n0 + r;
                float4 v = {0.f, 0.f, 0.f, 0.f};
                if (gn < G4) {
                    if (gk + 3 < IN_SZ) {
                        v = *reinterpret_cast<const float4*>(Wih + (size_t)gn * IN_SZ + gk);
                    } else {
                        const float* row = Wih + (size_t)gn * IN_SZ;
                        v.x = (gk + 0 < IN_SZ) ? row[gk + 0] : 0.f;
                        v.y = (gk + 1 < IN_SZ) ? row[gk + 1] : 0.f;
                        v.z = (gk + 2 < IN_SZ) ? row[gk + 2] : 0.f;
                        v.w = (gk + 3 < IN_SZ) ? row[gk + 3] : 0.f;
                    }
                }
                Bs[c + 0][r] = v.x; Bs[c + 1][r] = v.y;
                Bs[c + 2][r] = v.z; Bs[c + 3][r] = v.w;
            }
        }
        __syncthreads();
        #pragma unroll
        for (int k = 0; k < BK; ++k) {
            float a[8], b[8];
            *reinterpret_cast<float4*>(&a[0]) = *reinterpret_cast<const float4*>(&As[k][ty * 8]);
            *reinterpret_cast<float4*>(&a[4]) = *reinterpret_cast<const float4*>(&As[k][ty * 8 + 4]);
            *reinterpret_cast<float4*>(&b[0]) = *reinterpret_cast<const float4*>(&Bs[k][tx * 8]);
            *reinterpret_cast<float4*>(&b[4]) = *reinterpret_cast<const float4*>(&Bs[k][tx * 8 + 4]);
            #pragma unroll
            for (int i = 0; i < 8; ++i)
                #pragma unroll
                for (int j = 0; j < 8; ++j)
                    acc[i][j] = fmaf(a[i], b[j], acc[i][j]);
        }
        __syncthreads();
    }

    // epilogue: bias + store
    float bias[8];
    #pragma unroll
    for (int j = 0; j < 8; ++j) {
        const int n = n0 + tx * 8 + j;
        bias[j] = (n < G4) ? (bih[n] + bhh[n]) : 0.f;
    }
    #pragma unroll
    for (int i = 0; i < 8; ++i) {
        const int m = m0 + ty * 8 + i;
        if (m >= T) continue;
        #pragma unroll
        for (int j = 0; j < 8; ++j) {
            const int n = n0 + tx * 8 + j;
            if (n < G4) stxg_(&xg[(size_t)m * G4 + n], acc[i][j] + bias[j]);
        }
    }
}

// ---------------- Phase 2: register-resident recurrent kernel ----------------
// MODE 0: xg fp32; MODE 1: xg bf16.
template <int MODE>
__global__ __launch_bounds__(256, 1) void lstm_fast(
    const void* __restrict__ xg_v,
    const float* __restrict__ Whh,   // (4000, 1000)
    float* __restrict__ out,         // (T, 1000)
    unsigned* hb_u,                  // 2 * 1024 u32 (double-buffered, stamped)
    int T)
{
    __shared__ __align__(16) unsigned hs[2][1024];
    __shared__ float gsum[4][4][2];  // [wave][gate][elem]

    const int w = blockIdx.x, tid = threadIdx.x;
    const int wave = tid >> 6, lane = tid & 63;
    const int i16 = lane & 15, p = lane >> 4;       // p = gate for the dot
    const int we0 = w * 8 + wave * 2;               // this wave's 2 h-elements

    for (int i = tid; i < 2048; i += 256) ((unsigned*)hs)[i] = 0u;
    __syncthreads();

    // ---- weight preload into registers: rows (p*HID + we0), (.. + 1) ----
    const size_t rowA = (size_t)(p * HID + we0) * HID;
    const size_t rowB = rowA + HID;
    float4 wA[16], wB[16], hreg[16];
    #pragma unroll
    for (int m = 0; m < 15; ++m) {
        wA[m] = *reinterpret_cast<const float4*>(Whh + rowA + i16 * 4 + m * 64);
        wB[m] = *reinterpret_cast<const float4*>(Whh + rowB + i16 * 4 + m * 64);
    }
    if (i16 < 10) {
        wA[15] = *reinterpret_cast<const float4*>(Whh + rowA + 960 + i16 * 4);
        wB[15] = *reinterpret_cast<const float4*>(Whh + rowB + 960 + i16 * 4);
    } else {
        wA[15] = float4{0.f, 0.f, 0.f, 0.f};
        wB[15] = float4{0.f, 0.f, 0.f, 0.f};
    }

    // ---- wave-0 gate-lane mapping: lane = v*8 + gate*2 + e (lanes 0..31) ----
    const int gv_ = (lane >> 3) & 3;   // source wave v
    const int gp  = (lane >> 1) & 3;   // gate
    const int ge  = lane & 1;          // elem parity
    const int eg  = w * 8 + gv_ * 2 + ge;  // global h index for this lane
    const int shbase = (lane & ~7) | ge;   // owner-lane base for shfl combine
    float c_reg = 0.0f;                    // owner lanes (gp==0) of wave 0
    float xv = 0.0f;
    if (wave == 0 && lane < 32) {
        if (MODE == 0) xv = ((const float*)xg_v)[(size_t)gp * HID + eg];
        else           xv = __bfloat162float(((const __hip_bfloat16*)xg_v)[(size_t)gp * HID + eg]);
    }

    // ---- gather mapping (waves 1-3; 192 threads cover 250 uint4, dup tail) ----
    const int tid2 = tid - 64;                 // 0..191
    const int iA = tid2;
    const int iB = 192 + (tid2 % 58);          // covers 192..249 (duplicated)

    for (int t = 0;;) {
        const int rb = t & 1;

        // ---- h slice LDS -> regs ----
        #pragma unroll
        for (int m = 0; m < 15; ++m)
            hreg[m] = *reinterpret_cast<const float4*>(&hs[rb][i16 * 4 + m * 64]);
        hreg[15] = *reinterpret_cast<const float4*>(&hs[rb][960 + i16 * 4]);

        // ---- dot: 2 rows x 64 floats per lane ----
        float a0 = 0.f, a1 = 0.f, a2 = 0.f, a3 = 0.f;
        float b0 = 0.f, b1 = 0.f, b2 = 0.f, b3 = 0.f;
        #pragma unroll
        for (int m = 0; m < 16; ++m) {
            const float4 hv = hreg[m];
            const float sA = fmaf(wA[m].x, hv.x, fmaf(wA[m].y, hv.y,
                             fmaf(wA[m].z, hv.z, wA[m].w * hv.w)));
            const float sB = fmaf(wB[m].x, hv.x, fmaf(wB[m].y, hv.y,
                             fmaf(wB[m].z, hv.z, wB[m].w * hv.w)));
            if ((m & 3) == 0)      { a0 += sA; b0 += sB; }
            else if ((m & 3) == 1) { a1 += sA; b1 += sB; }
            else if ((m & 3) == 2) { a2 += sA; b2 += sB; }
            else                   { a3 += sA; b3 += sB; }
        }
        float rA = (a0 + a1) + (a2 + a3);
        float rB = (b0 + b1) + (b2 + b3);
        rA += __shfl_xor(rA, 1); rB += __shfl_xor(rB, 1);
        rA += __shfl_xor(rA, 2); rB += __shfl_xor(rB, 2);
        rA += __shfl_xor(rA, 4); rB += __shfl_xor(rB, 4);
        rA += __shfl_xor(rA, 8); rB += __shfl_xor(rB, 8);
        if (i16 == 0) { gsum[wave][p][0] = rA; gsum[wave][p][1] = rB; }
        __syncthreads();   // bar1: gsum complete, hs[rb] reads done

        // ---- wave 0: parallel gates, cell update, stamped publish ----
        if (wave == 0) {
            const float g = gsum[gv_][gp][ge] + xv;
            const float act = (gp == 2) ? tanh_fast(g) : sigm(g);
            const float iv = __shfl(act, shbase);
            const float fv = __shfl(act, shbase + 2);
            const float g2 = __shfl(act, shbase + 4);
            const float ov = __shfl(act, shbase + 6);
            if (lane < 32 && gp == 0) {    // owner lanes: v*8 + e
                c_reg = fv * c_reg + iv * g2;
                const float h = ov * tanh_fast(c_reg);
                out[(size_t)t * HID + eg] = h;
                const unsigned hb = (__float_as_uint(h) & ~3u) | (unsigned)((t + 1) & 3);
                __hip_atomic_store(hb_u + rb * 1024 + eg, hb,
                                   __ATOMIC_RELAXED, __HIP_MEMORY_SCOPE_AGENT);
            }
            // xg prefetch for next step (full step of latency cover; only in
            // wave 0's vmcnt — gather waves never wait on it)
            if (lane < 32 && t + 1 < T) {
                if (MODE == 0)
                    xv = ((const float*)xg_v)[(size_t)(t + 1) * G4 + gp * HID + eg];
                else
                    xv = __bfloat162float(((const __hip_bfloat16*)xg_v)
                                          [(size_t)(t + 1) * G4 + gp * HID + eg]);
            }
        }

        if (++t >= T) break;

        // ---- waves 1-3: retry-gather stamped h with clean vmcnt ----
        if (wave > 0) {
            const unsigned want = (unsigned)t & 3u;        // stamp of h^{t-1}
            const uint4* srcb =
                reinterpret_cast<const uint4*>(hb_u + ((t - 1) & 1) * 1024);
            uint4 vA, vB;
            for (;;) {
                asm volatile("global_load_dwordx4 %0, %2, off sc0 sc1\n\t"
                             "global_load_dwordx4 %1, %3, off sc0 sc1\n\t"
                             "s_waitcnt vmcnt(0)"
                             : "=&v"(vA), "=&v"(vB)
                             : "v"(srcb + iA), "v"(srcb + iB)
                             : "memory");
                const unsigned bad =
                    ((vA.x ^ want) | (vA.y ^ want) | (vA.z ^ want) | (vA.w ^ want) |
                     (vB.x ^ want) | (vB.y ^ want) | (vB.z ^ want) | (vB.w ^ want)) & 3u;
                if (bad == 0u) break;
            }
            reinterpret_cast<uint4*>(&hs[t & 1][0])[iA] = vA;
            reinterpret_cast<uint4*>(&hs[t & 1][0])[iB] = vB;  // dup-write, same value
        }
        __syncthreads();   // bar2: hs[t&1] ready
    }
}

// ---------------- legacy fallback (tiny ws): fused x-projection ----------------
__global__ __launch_bounds__(256, 1) void lstm_seq_legacy(
    const float* __restrict__ x,
    const float* __restrict__ Wih,
    const float* __restrict__ Whh,
    const float* __restrict__ bih,
    const float* __restrict__ bhh,
    float* __restrict__ out,
    float* hbuf, unsigned* flags, int T)
{
    __shared__ __align__(16) float h_s[HID];
    __shared__ __align__(16) float x_s[IN_SZ + 4];
    __shared__ float pre[4][EP_LEG];

    const int w = blockIdx.x, tid = threadIdx.x;
    const int wave = tid >> 6, lane = tid & 63;
    const int i16 = lane & 15, p = lane >> 4;
    const int e0 = w * EP_LEG;

    for (int i = tid; i < HID; i += 256) h_s[i] = 0.0f;
    for (int i = tid; i < IN_SZ; i += 256) x_s[i] = x[i];
    __syncthreads();

    const float* wb_h = Whh + ((size_t)wave * HID + e0) * HID;
    const float* wb_x = Wih + ((size_t)wave * HID + e0) * IN_SZ;
    float c_reg = 0.0f;
    float bsum[4] = {0.f, 0.f, 0.f, 0.f};
    if (wave == 0 && lane < EP_LEG) {
        #pragma unroll
        for (int g = 0; g < 4; ++g) {
            int n = g * HID + e0 + lane;
            bsum[g] = bih[n] + bhh[n];
        }
    }

    for (int t = 0;;) {
        #pragma unroll
        for (int pass = 0; pass < EP_LEG / 4; ++pass) {
            const int e = pass * 4 + p;
            const float* wr = wb_h + (size_t)e * HID;
            float a0 = 0.f, a1 = 0.f, a2 = 0.f, a3 = 0.f;
            #pragma unroll
            for (int m = 0; m < 15; ++m) {
                const int k = i16 * 4 + m * 64;
                const float4 wv = *reinterpret_cast<const float4*>(wr + k);
                const float4 hv = *reinterpret_cast<const float4*>(&h_s[k]);
                const float s = fmaf(wv.x, hv.x, fmaf(wv.y, hv.y, fmaf(wv.z, hv.z, wv.w * hv.w)));
                if ((m & 3) == 0) a0 += s; else if ((m & 3) == 1) a1 += s;
                else if ((m & 3) == 2) a2 += s; else a3 += s;
            }
            if (i16 < 10) {
                const int k = i16 * 4 + 960;
                const float4 wv = *reinterpret_cast<const float4*>(wr + k);
                const float4 hv = *reinterpret_cast<const float4*>(&h_s[k]);
                a3 += fmaf(wv.x, hv.x, fmaf(wv.y, hv.y, fmaf(wv.z, hv.z, wv.w * hv.w)));
            }
            const float* wrx = wb_x + (size_t)e * IN_SZ;
            #pragma unroll
            for (int m = 0; m < 9; ++m) {
                const int k = i16 * 4 + m * 64;
                const float4 wv = *reinterpret_cast<const float4*>(wrx + k);
                const float4 hv = *reinterpret_cast<const float4*>(&x_s[k]);
                const float s = fmaf(wv.x, hv.x, fmaf(wv.y, hv.y, fmaf(wv.z, hv.z, wv.w * hv.w)));
                if ((m & 3) == 0) a0 += s; else if ((m & 3) == 1) a1 += s;
                else if ((m & 3) == 2) a2 += s; else a3 += s;
            }
            if (i16 < 11) {
                const int k = i16 * 4 + 576;
                const float4 wv = *reinterpret_cast<const float4*>(wrx + k);
                const float4 hv = *reinterpret_cast<const float4*>(&x_s[k]);
                a3 += fmaf(wv.x, hv.x, fmaf(wv.y, hv.y, fmaf(wv.z, hv.z, wv.w * hv.w)));
            }
            float acc = (a0 + a1) + (a2 + a3);
            acc += __shfl_xor(acc, 1);
            acc += __shfl_xor(acc, 2);
            acc += __shfl_xor(acc, 4);
            acc += __shfl_xor(acc, 8);
            if (i16 == 0) pre[wave][e] = acc;
        }
        __syncthreads();

        if (wave == 0 && lane < EP_LEG) {
            const float gi = pre[0][lane] + bsum[0];
            const float gf = pre[1][lane] + bsum[1];
            const float gg = pre[2][lane] + bsum[2];
            const float go = pre[3][lane] + bsum[3];
            const float iv = sigm(gi);
            const float fv = sigm(gf);
            const float gv = tanh_fast(gg);
            const float ov = sigm(go);
            c_reg = fv * c_reg + iv * gv;
            const float h = ov * tanh_fast(c_reg);
            out[(size_t)t * HID + e0 + lane] = h;
            __hip_atomic_store(&hbuf[(t & 1) * 1024 + e0 + lane], h,
                               __ATOMIC_RELAXED, __HIP_MEMORY_SCOPE_AGENT);
        }
        if (++t >= T) break;
        if (wave == 0 && lane == 0) {
            asm volatile("s_waitcnt vmcnt(0)" ::: "memory");
            __hip_atomic_store(&flags[w], (unsigned)t,
                               __ATOMIC_RELAXED, __HIP_MEMORY_SCOPE_AGENT);
        }
        if (wave > 0) {
            if (lane < NW_LEG) {
                while (__hip_atomic_load(&flags[lane], __ATOMIC_RELAXED,
                                         __HIP_MEMORY_SCOPE_AGENT) < (unsigned)t) {}
            }
            const int rb = tid - 64;
            for (int i = rb; i < HID; i += 192) {
                h_s[i] = __hip_atomic_load(&hbuf[((t - 1) & 1) * 1024 + i],
                                           __ATOMIC_RELAXED, __HIP_MEMORY_SCOPE_AGENT);
            }
            for (int i = rb; i < IN_SZ; i += 192) x_s[i] = x[(size_t)t * IN_SZ + i];
        }
        __syncthreads();
    }
}

// ---------------- launch ----------------
extern "C" void kernel_launch(void* const* d_in, const int* in_sizes, int n_in,
                              void* d_out, int out_size, void* d_ws, size_t ws_size,
                              hipStream_t stream)
{
    const float* x   = (const float*)d_in[0];
    const float* Wih = (const float*)d_in[1];
    const float* Whh = (const float*)d_in[2];
    const float* bih = (const float*)d_in[3];
    const float* bhh = (const float*)d_in[4];
    float* out = (float*)d_out;
    const int T = in_sizes[0] / IN_SZ;

    char* ws = (char*)d_ws;
    unsigned* hb_u  = (unsigned*)ws;           // 2*1024 u32 = 8 KB (stamped h)
    unsigned* flags = (unsigned*)(ws + 8192);  // legacy only
    const size_t CTRL = 16384;
    hipMemsetAsync(d_ws, 0, CTRL, stream);     // zero h buffers + flags every call

    const size_t need32 = CTRL + (size_t)T * G4 * sizeof(float);
    const size_t need16 = CTRL + (size_t)T * G4 * sizeof(__hip_bfloat16);

    dim3 g1((G4 + 127) / 128, (T + 127) / 128), b1(256);

    if (ws_size >= need32) {
        float* xgbuf = (float*)(ws + CTRL);
        xg_gemm2<float><<<g1, b1, 0, stream>>>(x, Wih, bih, bhh, xgbuf, T);
        lstm_fast<0><<<dim3(NWF), dim3(256), 0, stream>>>(xgbuf, Whh, out, hb_u, T);
    } else if (ws_size >= need16) {
        __hip_bfloat16* xgbuf = (__hip_bfloat16*)(ws + CTRL);
        xg_gemm2<__hip_bfloat16><<<g1, b1, 0, stream>>>(x, Wih, bih, bhh, xgbuf, T);
        lstm_fast<1><<<dim3(NWF), dim3(256), 0, stream>>>(xgbuf, Whh, out, hb_u, T);
    } else {
        lstm_seq_legacy<<<dim3(NW_LEG), dim3(256), 0, stream>>>(
            x, Wih, Whh, bih, bhh, out, (float*)hb_u, flags, T);
    }
}